// Round 3
// baseline (1077.267 us; speedup 1.0000x reference)
//
#include <hip/hip_runtime.h>
#include <hip/hip_bf16.h>
#include <math.h>
#include <stdint.h>

typedef unsigned short u16;
typedef __bf16 bf16x8 __attribute__((ext_vector_type(8)));
typedef float f32x4 __attribute__((ext_vector_type(4)));
typedef __attribute__((address_space(1))) void gv_t;
typedef __attribute__((address_space(3))) void lv_t;

// ---------- helpers ----------
__device__ inline u16 f2bf(float f) {
    union { float f; uint32_t u; } v; v.f = f;
    uint32_t u = v.u;
    uint32_t r = (u + 0x7fffu + ((u >> 16) & 1u)) >> 16;  // RNE
    return (u16)r;
}
__device__ inline float gelu_tanh(float x) {
    float u = 0.7978845608028654f * x * (1.0f + 0.044715f * x * x);
    float e = __expf(2.0f * u);
    float t = 1.0f - 2.0f / (e + 1.0f);
    return 0.5f * x * (1.0f + t);
}

// ---------- gate ----------
__global__ __launch_bounds__(256) void gate_kernel(const float* __restrict__ x,
                                                   const float* __restrict__ Wg,
                                                   float* __restrict__ w4) {
    const int token = blockIdx.x * 4 + (threadIdx.x >> 6);
    const int lane  = threadIdx.x & 63;
    const float* xr = x + (size_t)token * 1024;
    float acc[16];
#pragma unroll
    for (int e = 0; e < 16; e++) acc[e] = 0.f;
#pragma unroll 4
    for (int d = lane; d < 1024; d += 64) {
        float xv = xr[d];
        const float4* wr_ = (const float4*)(Wg + (size_t)d * 16);
        float4 a0 = wr_[0], a1 = wr_[1], a2 = wr_[2], a3 = wr_[3];
        acc[0]  += xv * a0.x; acc[1]  += xv * a0.y; acc[2]  += xv * a0.z; acc[3]  += xv * a0.w;
        acc[4]  += xv * a1.x; acc[5]  += xv * a1.y; acc[6]  += xv * a1.z; acc[7]  += xv * a1.w;
        acc[8]  += xv * a2.x; acc[9]  += xv * a2.y; acc[10] += xv * a2.z; acc[11] += xv * a2.w;
        acc[12] += xv * a3.x; acc[13] += xv * a3.y; acc[14] += xv * a3.z; acc[15] += xv * a3.w;
    }
#pragma unroll
    for (int e = 0; e < 16; e++) {
        float v = acc[e];
        v += __shfl_xor(v, 32, 64);
        v += __shfl_xor(v, 16, 64);
        v += __shfl_xor(v, 8, 64);
        v += __shfl_xor(v, 4, 64);
        v += __shfl_xor(v, 2, 64);
        v += __shfl_xor(v, 1, 64);
        acc[e] = v;
    }
    if (lane == 0) {
        float l[16];
#pragma unroll
        for (int e = 0; e < 16; e++) l[e] = acc[e];
        int   bi4[4]; float bv4[4];
#pragma unroll
        for (int j = 0; j < 4; j++) {
            int bi = 0; float b = l[0];
#pragma unroll
            for (int e = 1; e < 16; e++) { if (l[e] > b) { b = l[e]; bi = e; } }
            bi4[j] = bi; bv4[j] = b; l[bi] = -INFINITY;
        }
        float mx = bv4[0];
        float den = 0.f;
#pragma unroll
        for (int j = 0; j < 4; j++) den += expf(bv4[j] - mx);
        float wout[4] = {0.f, 0.f, 0.f, 0.f};
#pragma unroll
        for (int j = 0; j < 4; j++)
            if (bi4[j] < 4) wout[bi4[j]] = expf(bv4[j] - mx) / den;
        float* o = w4 + (size_t)token * 4;
        o[0] = wout[0]; o[1] = wout[1]; o[2] = wout[2]; o[3] = wout[3];
    }
}

// ---------- vectorized cast x fp32 -> bf16 ----------
__global__ __launch_bounds__(256) void cast_x_kernel(const float* __restrict__ x,
                                                     u16* __restrict__ Xe, int nvec) {
    for (int i = blockIdx.x * blockDim.x + threadIdx.x; i < nvec; i += gridDim.x * blockDim.x) {
        const float4* s = (const float4*)(x + (size_t)i * 8);
        float4 a = s[0], b = s[1];
        union { u16 h[8]; uint4 q; } o;
        o.h[0] = f2bf(a.x); o.h[1] = f2bf(a.y); o.h[2] = f2bf(a.z); o.h[3] = f2bf(a.w);
        o.h[4] = f2bf(b.x); o.h[5] = f2bf(b.y); o.h[6] = f2bf(b.z); o.h[7] = f2bf(b.w);
        *(uint4*)(Xe + (size_t)i * 8) = o.q;
    }
}

// ---------- fused transpose + LoRA-fold ----------
__global__ __launch_bounds__(256) void weff_kernel(const float* __restrict__ src,
                                                   const float* __restrict__ Am,
                                                   const float* __restrict__ Bm,
                                                   u16* __restrict__ dst,
                                                   int Fdim, int lddst,
                                                   size_t s_est, size_t a_est, size_t b_est, size_t d_est) {
    const int e = blockIdx.z;
    src += e * s_est; Am += e * a_est; Bm += e * b_est; dst += e * d_est;
    __shared__ float t[32][33];
    __shared__ float sa[32][16];
    __shared__ float sb[16][32];
    const int tx = threadIdx.x, ty = threadIdx.y, tid = ty * 32 + tx;
    const int f0 = blockIdx.x * 32, k0 = blockIdx.y * 32;
#pragma unroll
    for (int i = ty; i < 32; i += 8) t[i][tx] = src[(size_t)(k0 + i) * Fdim + f0 + tx];
    for (int idx = tid; idx < 512; idx += 256) sa[idx >> 4][idx & 15] = Am[(size_t)(k0 + (idx >> 4)) * 16 + (idx & 15)];
    for (int idx = tid; idx < 512; idx += 256) sb[idx >> 5][idx & 31] = Bm[(size_t)(idx >> 5) * Fdim + f0 + (idx & 31)];
    __syncthreads();
#pragma unroll
    for (int i = ty; i < 32; i += 8) {
        float s = t[tx][i];
#pragma unroll
        for (int r = 0; r < 16; r++) s += sa[tx][r] * sb[r][i];
        dst[(size_t)(f0 + i) * lddst + k0 + tx] = f2bf(s);
    }
}

// ---------- counted-vmcnt pipelined GEMM: C = A[M][K] @ BT[N][K]^T ----------
// BM=256, step=32 K, 4 cyclic buffers, depth-3 prefetch, 8 waves (2Mx4N).
// EPI 0: Hout[m][n] = bf16(w4[m][tn>>4] * gelu(C))   (GEMM1, BN=256)
// EPI 1: Out[m][n]  = C (fp32 store)                 (GEMM2, BN=128)
template<int BN, int EPI>
__global__ __launch_bounds__(512, 2) void gemm_kernel(
    const u16* __restrict__ A, const u16* __restrict__ BT,
    const int lda, const int ldb, const int ntn, const int NSTEPS,
    u16* __restrict__ Hout, const int ldh, const float* __restrict__ w4,
    float* __restrict__ Out, const int ldo) {
    constexpr int NF  = BN / 64;    // B frags per wave (4 or 2)
    constexpr int BSW = BN / 128;   // B staging sweeps per step (2 or 1)
    constexpr int LPT = 2 + BSW;    // loads per thread per step
    __shared__ __align__(16) u16 As[4][256 * 32];
    __shared__ __align__(16) u16 Bs[4][BN * 32];

    const int tid = threadIdx.x;
    const int w = tid >> 6, lane = tid & 63;
    const int wr = w >> 2, wc = w & 3;

    // bijective XCD chunked swizzle (gridDim.x % 8 == 0)
    const int chunk = gridDim.x >> 3;
    const int swz = (blockIdx.x & 7) * chunk + (blockIdx.x >> 3);
    const int tm = swz / ntn, tn = swz % ntn;

    // staging: wave w covers rows w*16..w*16+15 of each 128-row sweep;
    // lane l -> phys row w*16 + (l>>2), phys 16B-chunk l&3.
    // source pre-swizzled: logical chunk = (l&3) ^ ((l>>2)&3)   [rule 21]
    const int prow = lane >> 2;
    const int cl = (lane & 3) ^ (prow & 3);
    const u16* gA = A  + (size_t)(tm * 256 + w * 16 + prow) * lda + cl * 8;
    const u16* gB = BT + (size_t)(tn * BN  + w * 16 + prow) * ldb + cl * 8;
    const int lbase = (w * 16) * 32;  // wave-uniform LDS base (elements)

    // fragment read: lane = (r, kq); element (row,k) at row*32 + ((k>>3)^(row&3))*8
    const int r = lane & 15, kq = lane >> 4;
    const int koff = ((kq ^ (r & 3)) << 3);
    const int rowA = (wr * 128 + r) * 32 + koff;
    const int rowB = (wc * (BN / 4) + r) * 32 + koff;

    f32x4 acc[8][NF];
#pragma unroll
    for (int m = 0; m < 8; m++)
#pragma unroll
        for (int n = 0; n < NF; n++) acc[m][n] = (f32x4){0.f, 0.f, 0.f, 0.f};

    auto stage = [&](int s) {
        const int buf = s & 3;
        const size_t ko = (size_t)s * 32;
        u16* da = (u16*)&As[buf][lbase];
        __builtin_amdgcn_global_load_lds((gv_t*)(u16*)(gA + ko),                      (lv_t*)da, 16, 0, 0);
        __builtin_amdgcn_global_load_lds((gv_t*)(u16*)(gA + ko + (size_t)128 * lda), (lv_t*)(da + 128 * 32), 16, 0, 0);
        u16* db = (u16*)&Bs[buf][lbase];
        __builtin_amdgcn_global_load_lds((gv_t*)(u16*)(gB + ko),                      (lv_t*)db, 16, 0, 0);
        if constexpr (BSW == 2)
            __builtin_amdgcn_global_load_lds((gv_t*)(u16*)(gB + ko + (size_t)128 * ldb), (lv_t*)(db + 128 * 32), 16, 0, 0);
    };

    // prologue: stage steps 0..2 (oldest first)
    stage(0); stage(1); stage(2);

#define GSTEP(S, VW, PF)                                                          \
    {                                                                             \
        asm volatile("s_waitcnt vmcnt(%0)" :: "n"(VW) : "memory");                \
        __builtin_amdgcn_s_barrier();                                             \
        __builtin_amdgcn_sched_barrier(0);                                        \
        if (PF) stage((S) + 3);                                                   \
        const int buf_ = (S) & 3;                                                 \
        bf16x8 af[8], bv[NF];                                                     \
        _Pragma("unroll")                                                         \
        for (int m = 0; m < 8; m++) af[m] = *(const bf16x8*)&As[buf_][rowA + m * 512]; \
        _Pragma("unroll")                                                         \
        for (int n = 0; n < NF; n++) bv[n] = *(const bf16x8*)&Bs[buf_][rowB + n * 512]; \
        asm volatile("s_waitcnt lgkmcnt(0)" ::: "memory");                        \
        __builtin_amdgcn_sched_barrier(0);                                        \
        __builtin_amdgcn_s_setprio(1);                                            \
        _Pragma("unroll")                                                         \
        for (int m = 0; m < 8; m++)                                               \
            _Pragma("unroll")                                                     \
            for (int n = 0; n < NF; n++)                                          \
                acc[m][n] = __builtin_amdgcn_mfma_f32_16x16x32_bf16(af[m], bv[n], acc[m][n], 0, 0, 0); \
        __builtin_amdgcn_s_setprio(0);                                            \
    }

    // main loop: counted vmcnt (never 0); steady-state 2 steps in flight after wait
    for (int s = 0; s < NSTEPS - 2; ++s) {
        GSTEP(s, 2 * LPT, s + 3 < NSTEPS);
    }
    // peeled tail: fewer steps outstanding
    GSTEP(NSTEPS - 2, LPT, false);
    GSTEP(NSTEPS - 1, 0, false);
#undef GSTEP

    // ---- epilogue ----
    const int rbase = tm * 256 + wr * 128 + kq * 4;
    const int cbase = tn * BN + wc * (BN / 4) + r;
    if (EPI == 0) {
        const int e = tn >> 4;  // BN=256: 16 tiles per 4096-wide expert block
#pragma unroll
        for (int m = 0; m < 8; m++) {
#pragma unroll
            for (int q = 0; q < 4; q++) {
                const int row = rbase + m * 16 + q;
                const float wgt = w4[(size_t)row * 4 + e];
                u16* hp = Hout + (size_t)row * ldh + cbase;
#pragma unroll
                for (int n = 0; n < NF; n++)
                    hp[n * 16] = f2bf(wgt * gelu_tanh(acc[m][n][q]));
            }
        }
    } else {
#pragma unroll
        for (int m = 0; m < 8; m++) {
#pragma unroll
            for (int q = 0; q < 4; q++) {
                const int row = rbase + m * 16 + q;
                float* op = Out + (size_t)row * ldo + cbase;
#pragma unroll
                for (int n = 0; n < NF; n++) op[n * 16] = acc[m][n][q];
            }
        }
    }
}

// ---------- launch ----------
extern "C" void kernel_launch(void* const* d_in, const int* in_sizes, int n_in,
                              void* d_out, int out_size, void* d_ws, size_t ws_size,
                              hipStream_t stream) {
    (void)in_sizes; (void)n_in; (void)out_size;
    const float* x  = (const float*)d_in[0];
    const float* Wg = (const float*)d_in[1];
    const float* W1 = (const float*)d_in[2];
    const float* A1 = (const float*)d_in[3];
    const float* B1 = (const float*)d_in[4];
    const float* W2 = (const float*)d_in[5];
    const float* A2 = (const float*)d_in[6];
    const float* B2 = (const float*)d_in[7];
    float* out = (float*)d_out;

    const int N = 8192;

    const size_t need = 131072
                      + (size_t)8192 * 1024 * 2
                      + (size_t)8192 * 16384 * 2
                      + (size_t)16384 * 1024 * 2
                      + (size_t)1024 * 16384 * 2;
    if (ws_size < need) return;  // fail visibly rather than corrupt

    char* p = (char*)d_ws;
    float* w4 = (float*)p; p += 131072;
    u16* Xe   = (u16*)p;   p += (size_t)8192 * 1024 * 2;
    u16* Hs   = (u16*)p;   p += (size_t)8192 * 16384 * 2;
    u16* W1T  = (u16*)p;   p += (size_t)16384 * 1024 * 2;
    u16* W2T  = (u16*)p;   p += (size_t)1024 * 16384 * 2;

    gate_kernel<<<N / 4, 256, 0, stream>>>(x, Wg, w4);
    cast_x_kernel<<<2048, 256, 0, stream>>>(x, Xe, N * 1024 / 8);
    // W1eff^T[e*4096+f][k] = bf16(W1[e][k][f] + sum_r A1[e][k][r]*B1[e][r][f])
    weff_kernel<<<dim3(128, 32, 4), dim3(32, 8), 0, stream>>>(
        W1, A1, B1, W1T, 4096, 1024,
        (size_t)1024 * 4096, (size_t)1024 * 16, (size_t)16 * 4096, (size_t)4096 * 1024);
    // W2eff^T[d][e*4096+k] = bf16(W2[e][k][d] + sum_r A2[e][k][r]*B2[e][r][d])
    weff_kernel<<<dim3(32, 128, 4), dim3(32, 8), 0, stream>>>(
        W2, A2, B2, W2T, 1024, 16384,
        (size_t)4096 * 1024, (size_t)4096 * 16, (size_t)16 * 1024, (size_t)4096);
    // Hs[m][e*4096+f] = bf16(w4[m][e] * gelu(Xe @ W1eff^T))
    gemm_kernel<256, 0><<<(N / 256) * 64, 512, 0, stream>>>(
        Xe, W1T, 1024, 1024, 64, 32, Hs, 16384, w4, nullptr, 0);
    // out = Hs @ W2eff^T   (w folded into Hs; K = 16384 spans all 4 experts)
    gemm_kernel<128, 1><<<(N / 256) * 8, 512, 0, stream>>>(
        Hs, W2T, 16384, 16384, 8, 512, nullptr, 0, nullptr, nullptr ? nullptr : out, 1024);
}

// Round 4
// 1048.660 us; speedup vs baseline: 1.0273x; 1.0273x over previous
//
#include <hip/hip_runtime.h>
#include <hip/hip_bf16.h>
#include <math.h>
#include <stdint.h>

typedef unsigned short u16;
typedef __bf16 bf16x8 __attribute__((ext_vector_type(8)));
typedef float f32x4 __attribute__((ext_vector_type(4)));
typedef __attribute__((address_space(1))) void gv_t;
typedef __attribute__((address_space(3))) void lv_t;

// ---------- helpers ----------
__device__ inline u16 f2bf(float f) {
    union { float f; uint32_t u; } v; v.f = f;
    uint32_t u = v.u;
    uint32_t r = (u + 0x7fffu + ((u >> 16) & 1u)) >> 16;  // RNE
    return (u16)r;
}
__device__ inline float gelu_tanh(float x) {
    float u = 0.7978845608028654f * x * (1.0f + 0.044715f * x * x);
    float e = __expf(2.0f * u);
    float t = 1.0f - 2.0f / (e + 1.0f);
    return 0.5f * x * (1.0f + t);
}

// ---------- gate ----------
__global__ __launch_bounds__(256) void gate_kernel(const float* __restrict__ x,
                                                   const float* __restrict__ Wg,
                                                   float* __restrict__ w4) {
    const int token = blockIdx.x * 4 + (threadIdx.x >> 6);
    const int lane  = threadIdx.x & 63;
    const float* xr = x + (size_t)token * 1024;
    float acc[16];
#pragma unroll
    for (int e = 0; e < 16; e++) acc[e] = 0.f;
#pragma unroll 4
    for (int d = lane; d < 1024; d += 64) {
        float xv = xr[d];
        const float4* wr_ = (const float4*)(Wg + (size_t)d * 16);
        float4 a0 = wr_[0], a1 = wr_[1], a2 = wr_[2], a3 = wr_[3];
        acc[0]  += xv * a0.x; acc[1]  += xv * a0.y; acc[2]  += xv * a0.z; acc[3]  += xv * a0.w;
        acc[4]  += xv * a1.x; acc[5]  += xv * a1.y; acc[6]  += xv * a1.z; acc[7]  += xv * a1.w;
        acc[8]  += xv * a2.x; acc[9]  += xv * a2.y; acc[10] += xv * a2.z; acc[11] += xv * a2.w;
        acc[12] += xv * a3.x; acc[13] += xv * a3.y; acc[14] += xv * a3.z; acc[15] += xv * a3.w;
    }
#pragma unroll
    for (int e = 0; e < 16; e++) {
        float v = acc[e];
        v += __shfl_xor(v, 32, 64);
        v += __shfl_xor(v, 16, 64);
        v += __shfl_xor(v, 8, 64);
        v += __shfl_xor(v, 4, 64);
        v += __shfl_xor(v, 2, 64);
        v += __shfl_xor(v, 1, 64);
        acc[e] = v;
    }
    if (lane == 0) {
        float l[16];
#pragma unroll
        for (int e = 0; e < 16; e++) l[e] = acc[e];
        int   bi4[4]; float bv4[4];
#pragma unroll
        for (int j = 0; j < 4; j++) {
            int bi = 0; float b = l[0];
#pragma unroll
            for (int e = 1; e < 16; e++) { if (l[e] > b) { b = l[e]; bi = e; } }
            bi4[j] = bi; bv4[j] = b; l[bi] = -INFINITY;
        }
        float mx = bv4[0];
        float den = 0.f;
#pragma unroll
        for (int j = 0; j < 4; j++) den += expf(bv4[j] - mx);
        float wout[4] = {0.f, 0.f, 0.f, 0.f};
#pragma unroll
        for (int j = 0; j < 4; j++)
            if (bi4[j] < 4) wout[bi4[j]] = expf(bv4[j] - mx) / den;
        float* o = w4 + (size_t)token * 4;
        o[0] = wout[0]; o[1] = wout[1]; o[2] = wout[2]; o[3] = wout[3];
    }
}

// ---------- vectorized cast x fp32 -> bf16 ----------
__global__ __launch_bounds__(256) void cast_x_kernel(const float* __restrict__ x,
                                                     u16* __restrict__ Xe, int nvec) {
    for (int i = blockIdx.x * blockDim.x + threadIdx.x; i < nvec; i += gridDim.x * blockDim.x) {
        const float4* s = (const float4*)(x + (size_t)i * 8);
        float4 a = s[0], b = s[1];
        union { u16 h[8]; uint4 q; } o;
        o.h[0] = f2bf(a.x); o.h[1] = f2bf(a.y); o.h[2] = f2bf(a.z); o.h[3] = f2bf(a.w);
        o.h[4] = f2bf(b.x); o.h[5] = f2bf(b.y); o.h[6] = f2bf(b.z); o.h[7] = f2bf(b.w);
        *(uint4*)(Xe + (size_t)i * 8) = o.q;
    }
}

// ---------- fused transpose + LoRA-fold ----------
__global__ __launch_bounds__(256) void weff_kernel(const float* __restrict__ src,
                                                   const float* __restrict__ Am,
                                                   const float* __restrict__ Bm,
                                                   u16* __restrict__ dst,
                                                   int Fdim, int lddst,
                                                   size_t s_est, size_t a_est, size_t b_est, size_t d_est) {
    const int e = blockIdx.z;
    src += e * s_est; Am += e * a_est; Bm += e * b_est; dst += e * d_est;
    __shared__ float t[32][33];
    __shared__ float sa[32][16];
    __shared__ float sb[16][32];
    const int tx = threadIdx.x, ty = threadIdx.y, tid = ty * 32 + tx;
    const int f0 = blockIdx.x * 32, k0 = blockIdx.y * 32;
#pragma unroll
    for (int i = ty; i < 32; i += 8) t[i][tx] = src[(size_t)(k0 + i) * Fdim + f0 + tx];
    for (int idx = tid; idx < 512; idx += 256) sa[idx >> 4][idx & 15] = Am[(size_t)(k0 + (idx >> 4)) * 16 + (idx & 15)];
    for (int idx = tid; idx < 512; idx += 256) sb[idx >> 5][idx & 31] = Bm[(size_t)(idx >> 5) * Fdim + f0 + (idx & 31)];
    __syncthreads();
#pragma unroll
    for (int i = ty; i < 32; i += 8) {
        float s = t[tx][i];
#pragma unroll
        for (int r = 0; r < 16; r++) s += sa[tx][r] * sb[r][i];
        dst[(size_t)(f0 + i) * lddst + k0 + tx] = f2bf(s);
    }
}

// ---------- counted-vmcnt pipelined GEMM: C = A[M][K] @ BT[N][K]^T ----------
// BM=256, step=32 K, 4 cyclic buffers, depth-3 prefetch, 8 waves (WM x WN).
// LDS layout: two 32-el rows packed per 128B line; 8x16B chunks; phys chunk
// p = ((row&1)*4 + kchunk) ^ (line&7). Conflict-free for both the lane-linear
// global_load_lds writes (inverse-swizzled global source) and ds_read_b128.
// EPI 0: Hout[m][n] = bf16(w4[m][tn>>4] * gelu(C))   (GEMM1)
// EPI 1: Out[m][n]  = C (fp32 store)                 (GEMM2)
template<int BN, int WM, int WN, int EPI>
__global__ __launch_bounds__(512, 2) void gemm_kernel(
    const u16* __restrict__ A, const u16* __restrict__ BT,
    const int lda, const int ldb, const int ntn, const int NSTEPS,
    u16* __restrict__ Hout, const int ldh, const float* __restrict__ w4,
    float* __restrict__ Out, const int ldo) {
    constexpr int MROWS = 256 / WM, NCOLS = BN / WN;
    constexpr int MFR = MROWS / 16, NFR = NCOLS / 16;
    constexpr int BSW = BN / 128;        // B staging sweeps per step
    constexpr int LPT = 2 + BSW;         // VMEM instrs per thread per stage()
    __shared__ __align__(16) u16 As[4][128 * 64];
    __shared__ __align__(16) u16 Bs[4][(BN / 2) * 64];

    const int tid = threadIdx.x;
    const int w = tid >> 6, lane = tid & 63;
    const int wr = w / WN, wc = w % WN;

    // bijective XCD chunked swizzle (gridDim.x % 8 == 0)
    const int chunk = gridDim.x >> 3;
    const int swz = (blockIdx.x & 7) * chunk + (blockIdx.x >> 3);
    const int tm = swz / ntn, tn = swz % ntn;

    // ---- staging addressing (rule 21: linear LDS dest, inverse-swizzled src) ----
    // lane l -> phys line (w*8 + (l>>3)), phys chunk l&7.
    // logical: c = (l&7)^(l>>3); row = base + (l>>3)*2 + (c>>2); kchunk = c&3.
    const int il  = lane >> 3;
    const int cch = (lane & 7) ^ il;
    const int rowoff = il * 2 + (cch >> 2);
    const int kch = cch & 3;
    const u16* gA = A  + (size_t)(tm * 256 + w * 16 + rowoff) * lda + kch * 8;
    const u16* gB = BT + (size_t)(tn * BN  + w * 16 + rowoff) * ldb + kch * 8;
    const int sdl = (w * 8) * 64;  // wave-uniform LDS dest (elements)

    // ---- fragment read addressing ----
    // lane = (r = lane&15, kq = lane>>4); element (row,kq): line=row>>1,
    // p = ((row&1)*4+kq) ^ (line&7); addr_el = line*64 + p*8.
    // With row = wbase + mi*16 + r and wbase/2, mi*8 both ≡ 0 (mod 8):
    // addr_el = (wbase/2 + (r>>1))*64 + ((((r&1)<<2)|kq) ^ (r>>1))*8 + mi*512.
    const int r = lane & 15, kq = lane >> 4;
    const int psw = ((((r & 1) << 2) | kq) ^ (r >> 1)) << 3;
    const int elA = (wr * (MROWS / 2) + (r >> 1)) * 64 + psw;
    const int elB = (wc * (NCOLS / 2) + (r >> 1)) * 64 + psw;

    f32x4 acc[MFR][NFR];
#pragma unroll
    for (int m = 0; m < MFR; m++)
#pragma unroll
        for (int n = 0; n < NFR; n++) acc[m][n] = (f32x4){0.f, 0.f, 0.f, 0.f};

    auto stage = [&](int s) {
        const int buf = s & 3;
        const size_t ko = (size_t)s * 32;
        u16* da = (u16*)&As[buf][sdl];
        __builtin_amdgcn_global_load_lds((gv_t*)(u16*)(gA + ko),                      (lv_t*)da, 16, 0, 0);
        __builtin_amdgcn_global_load_lds((gv_t*)(u16*)(gA + ko + (size_t)128 * lda), (lv_t*)(da + 64 * 64), 16, 0, 0);
        u16* db = (u16*)&Bs[buf][sdl];
        __builtin_amdgcn_global_load_lds((gv_t*)(u16*)(gB + ko),                      (lv_t*)db, 16, 0, 0);
        if constexpr (BSW == 2)
            __builtin_amdgcn_global_load_lds((gv_t*)(u16*)(gB + ko + (size_t)128 * ldb), (lv_t*)(db + 64 * 64), 16, 0, 0);
    };

    // prologue: stage steps 0..2 (oldest first)
    stage(0); stage(1); stage(2);

#define GSTEP(S, VW, PF)                                                          \
    {                                                                             \
        asm volatile("s_waitcnt vmcnt(%0)" :: "n"(VW) : "memory");                \
        __builtin_amdgcn_s_barrier();                                             \
        __builtin_amdgcn_sched_barrier(0);                                        \
        if (PF) stage((S) + 3);                                                   \
        const int buf_ = (S) & 3;                                                 \
        bf16x8 af[MFR], bv[NFR];                                                  \
        _Pragma("unroll")                                                         \
        for (int m = 0; m < MFR; m++) af[m] = *(const bf16x8*)&As[buf_][elA + m * 512]; \
        _Pragma("unroll")                                                         \
        for (int n = 0; n < NFR; n++) bv[n] = *(const bf16x8*)&Bs[buf_][elB + n * 512]; \
        asm volatile("s_waitcnt lgkmcnt(0)" ::: "memory");                        \
        __builtin_amdgcn_sched_barrier(0);                                        \
        __builtin_amdgcn_s_setprio(1);                                            \
        _Pragma("unroll")                                                         \
        for (int m = 0; m < MFR; m++)                                             \
            _Pragma("unroll")                                                     \
            for (int n = 0; n < NFR; n++)                                         \
                acc[m][n] = __builtin_amdgcn_mfma_f32_16x16x32_bf16(af[m], bv[n], acc[m][n], 0, 0, 0); \
        __builtin_amdgcn_s_setprio(0);                                            \
    }

    // main loop: counted vmcnt (never 0 until the tail)
    for (int s = 0; s < NSTEPS - 2; ++s) {
        GSTEP(s, 2 * LPT, s + 3 < NSTEPS);
    }
    GSTEP(NSTEPS - 2, LPT, false);
    GSTEP(NSTEPS - 1, 0, false);
#undef GSTEP

    // ---- epilogue (C/D: col = lane&15 -> B-col r; row = kq*4 + q) ----
    const int rbase = tm * 256 + wr * MROWS + kq * 4;
    const int cbase = tn * BN + wc * NCOLS + r;
    if (EPI == 0) {
        const int e = tn >> 4;  // BN=256: 16 tiles per 4096-wide expert block
#pragma unroll
        for (int m = 0; m < MFR; m++) {
#pragma unroll
            for (int q = 0; q < 4; q++) {
                const int row = rbase + m * 16 + q;
                const float wgt = w4[(size_t)row * 4 + e];
                u16* hp = Hout + (size_t)row * ldh + cbase;
#pragma unroll
                for (int n = 0; n < NFR; n++)
                    hp[n * 16] = f2bf(wgt * gelu_tanh(acc[m][n][q]));
            }
        }
    } else {
#pragma unroll
        for (int m = 0; m < MFR; m++) {
#pragma unroll
            for (int q = 0; q < 4; q++) {
                const int row = rbase + m * 16 + q;
                float* op = Out + (size_t)row * ldo + cbase;
#pragma unroll
                for (int n = 0; n < NFR; n++) op[n * 16] = acc[m][n][q];
            }
        }
    }
}

// ---------- launch ----------
extern "C" void kernel_launch(void* const* d_in, const int* in_sizes, int n_in,
                              void* d_out, int out_size, void* d_ws, size_t ws_size,
                              hipStream_t stream) {
    (void)in_sizes; (void)n_in; (void)out_size;
    const float* x  = (const float*)d_in[0];
    const float* Wg = (const float*)d_in[1];
    const float* W1 = (const float*)d_in[2];
    const float* A1 = (const float*)d_in[3];
    const float* B1 = (const float*)d_in[4];
    const float* W2 = (const float*)d_in[5];
    const float* A2 = (const float*)d_in[6];
    const float* B2 = (const float*)d_in[7];
    float* out = (float*)d_out;

    const int N = 8192;

    const size_t need = 131072
                      + (size_t)8192 * 1024 * 2
                      + (size_t)8192 * 16384 * 2
                      + (size_t)16384 * 1024 * 2
                      + (size_t)1024 * 16384 * 2;
    if (ws_size < need) return;  // fail visibly rather than corrupt

    char* p = (char*)d_ws;
    float* w4 = (float*)p; p += 131072;
    u16* Xe   = (u16*)p;   p += (size_t)8192 * 1024 * 2;
    u16* Hs   = (u16*)p;   p += (size_t)8192 * 16384 * 2;
    u16* W1T  = (u16*)p;   p += (size_t)16384 * 1024 * 2;
    u16* W2T  = (u16*)p;   p += (size_t)1024 * 16384 * 2;

    gate_kernel<<<N / 4, 256, 0, stream>>>(x, Wg, w4);
    cast_x_kernel<<<2048, 256, 0, stream>>>(x, Xe, N * 1024 / 8);
    // W1eff^T[e*4096+f][k] = bf16(W1[e][k][f] + sum_r A1[e][k][r]*B1[e][r][f])
    weff_kernel<<<dim3(128, 32, 4), dim3(32, 8), 0, stream>>>(
        W1, A1, B1, W1T, 4096, 1024,
        (size_t)1024 * 4096, (size_t)1024 * 16, (size_t)16 * 4096, (size_t)4096 * 1024);
    // W2eff^T[d][e*4096+k] = bf16(W2[e][k][d] + sum_r A2[e][k][r]*B2[e][r][d])
    weff_kernel<<<dim3(32, 128, 4), dim3(32, 8), 0, stream>>>(
        W2, A2, B2, W2T, 1024, 16384,
        (size_t)4096 * 1024, (size_t)4096 * 16, (size_t)16 * 1024, (size_t)4096);
    // Hs[m][e*4096+f] = bf16(w4[m][e] * gelu(Xe @ W1eff^T)); waves 2M x 4N
    gemm_kernel<256, 2, 4, 0><<<(N / 256) * 64, 512, 0, stream>>>(
        Xe, W1T, 1024, 1024, 64, 32, Hs, 16384, w4, nullptr, 0);
    // out = Hs @ W2eff^T (w folded into Hs; K=16384 spans all 4 experts); waves 4M x 2N
    gemm_kernel<128, 4, 2, 1><<<(N / 256) * 8, 512, 0, stream>>>(
        Hs, W2T, 16384, 16384, 8, 512, nullptr, 0, nullptr, out, 1024);
}

// Round 5
// 833.932 us; speedup vs baseline: 1.2918x; 1.2575x over previous
//
#include <hip/hip_runtime.h>
#include <hip/hip_bf16.h>
#include <math.h>
#include <stdint.h>

typedef unsigned short u16;
typedef __bf16 bf16x8 __attribute__((ext_vector_type(8)));
typedef float f32x4 __attribute__((ext_vector_type(4)));
typedef __attribute__((address_space(1))) void gv_t;
typedef __attribute__((address_space(3))) void lv_t;

// ---------- helpers ----------
__device__ inline u16 f2bf(float f) {
    union { float f; uint32_t u; } v; v.f = f;
    uint32_t u = v.u;
    uint32_t r = (u + 0x7fffu + ((u >> 16) & 1u)) >> 16;  // RNE
    return (u16)r;
}
__device__ inline float gelu_tanh(float x) {
    float u = 0.7978845608028654f * x * (1.0f + 0.044715f * x * x);
    float e = __expf(2.0f * u);
    float t = 1.0f - 2.0f / (e + 1.0f);
    return 0.5f * x * (1.0f + t);
}

// ---------- gate ----------
__global__ __launch_bounds__(256) void gate_kernel(const float* __restrict__ x,
                                                   const float* __restrict__ Wg,
                                                   float* __restrict__ w4) {
    const int token = blockIdx.x * 4 + (threadIdx.x >> 6);
    const int lane  = threadIdx.x & 63;
    const float* xr = x + (size_t)token * 1024;
    float acc[16];
#pragma unroll
    for (int e = 0; e < 16; e++) acc[e] = 0.f;
#pragma unroll 4
    for (int d = lane; d < 1024; d += 64) {
        float xv = xr[d];
        const float4* wr_ = (const float4*)(Wg + (size_t)d * 16);
        float4 a0 = wr_[0], a1 = wr_[1], a2 = wr_[2], a3 = wr_[3];
        acc[0]  += xv * a0.x; acc[1]  += xv * a0.y; acc[2]  += xv * a0.z; acc[3]  += xv * a0.w;
        acc[4]  += xv * a1.x; acc[5]  += xv * a1.y; acc[6]  += xv * a1.z; acc[7]  += xv * a1.w;
        acc[8]  += xv * a2.x; acc[9]  += xv * a2.y; acc[10] += xv * a2.z; acc[11] += xv * a2.w;
        acc[12] += xv * a3.x; acc[13] += xv * a3.y; acc[14] += xv * a3.z; acc[15] += xv * a3.w;
    }
#pragma unroll
    for (int e = 0; e < 16; e++) {
        float v = acc[e];
        v += __shfl_xor(v, 32, 64);
        v += __shfl_xor(v, 16, 64);
        v += __shfl_xor(v, 8, 64);
        v += __shfl_xor(v, 4, 64);
        v += __shfl_xor(v, 2, 64);
        v += __shfl_xor(v, 1, 64);
        acc[e] = v;
    }
    if (lane == 0) {
        float l[16];
#pragma unroll
        for (int e = 0; e < 16; e++) l[e] = acc[e];
        int   bi4[4]; float bv4[4];
#pragma unroll
        for (int j = 0; j < 4; j++) {
            int bi = 0; float b = l[0];
#pragma unroll
            for (int e = 1; e < 16; e++) { if (l[e] > b) { b = l[e]; bi = e; } }
            bi4[j] = bi; bv4[j] = b; l[bi] = -INFINITY;
        }
        float mx = bv4[0];
        float den = 0.f;
#pragma unroll
        for (int j = 0; j < 4; j++) den += expf(bv4[j] - mx);
        float wout[4] = {0.f, 0.f, 0.f, 0.f};
#pragma unroll
        for (int j = 0; j < 4; j++)
            if (bi4[j] < 4) wout[bi4[j]] = expf(bv4[j] - mx) / den;
        float* o = w4 + (size_t)token * 4;
        o[0] = wout[0]; o[1] = wout[1]; o[2] = wout[2]; o[3] = wout[3];
    }
}

// ---------- vectorized cast x fp32 -> bf16 ----------
__global__ __launch_bounds__(256) void cast_x_kernel(const float* __restrict__ x,
                                                     u16* __restrict__ Xe, int nvec) {
    for (int i = blockIdx.x * blockDim.x + threadIdx.x; i < nvec; i += gridDim.x * blockDim.x) {
        const float4* s = (const float4*)(x + (size_t)i * 8);
        float4 a = s[0], b = s[1];
        union { u16 h[8]; uint4 q; } o;
        o.h[0] = f2bf(a.x); o.h[1] = f2bf(a.y); o.h[2] = f2bf(a.z); o.h[3] = f2bf(a.w);
        o.h[4] = f2bf(b.x); o.h[5] = f2bf(b.y); o.h[6] = f2bf(b.z); o.h[7] = f2bf(b.w);
        *(uint4*)(Xe + (size_t)i * 8) = o.q;
    }
}

// ---------- fused transpose + LoRA-fold ----------
__global__ __launch_bounds__(256) void weff_kernel(const float* __restrict__ src,
                                                   const float* __restrict__ Am,
                                                   const float* __restrict__ Bm,
                                                   u16* __restrict__ dst,
                                                   int Fdim, int lddst,
                                                   size_t s_est, size_t a_est, size_t b_est, size_t d_est) {
    const int e = blockIdx.z;
    src += e * s_est; Am += e * a_est; Bm += e * b_est; dst += e * d_est;
    __shared__ float t[32][33];
    __shared__ float sa[32][16];
    __shared__ float sb[16][32];
    const int tx = threadIdx.x, ty = threadIdx.y, tid = ty * 32 + tx;
    const int f0 = blockIdx.x * 32, k0 = blockIdx.y * 32;
#pragma unroll
    for (int i = ty; i < 32; i += 8) t[i][tx] = src[(size_t)(k0 + i) * Fdim + f0 + tx];
    for (int idx = tid; idx < 512; idx += 256) sa[idx >> 4][idx & 15] = Am[(size_t)(k0 + (idx >> 4)) * 16 + (idx & 15)];
    for (int idx = tid; idx < 512; idx += 256) sb[idx >> 5][idx & 31] = Bm[(size_t)(idx >> 5) * Fdim + f0 + (idx & 31)];
    __syncthreads();
#pragma unroll
    for (int i = ty; i < 32; i += 8) {
        float s = t[tx][i];
#pragma unroll
        for (int r = 0; r < 16; r++) s += sa[tx][r] * sb[r][i];
        dst[(size_t)(f0 + i) * lddst + k0 + tx] = f2bf(s);
    }
}

// ---------- out += part ----------
__global__ __launch_bounds__(256) void add_kernel(float* __restrict__ out,
                                                  const float* __restrict__ part, int n4) {
    for (int i = blockIdx.x * blockDim.x + threadIdx.x; i < n4; i += gridDim.x * blockDim.x) {
        float4 o = ((float4*)out)[i];
        float4 p = ((const float4*)part)[i];
        o.x += p.x; o.y += p.y; o.z += p.z; o.w += p.w;
        ((float4*)out)[i] = o;
    }
}

// ---------- 8-phase 256x256 GEMM (m201 template): C = A @ BT^T ----------
// BK=64 (2 kh sub-blocks of 32), 2 LDS tile-buffers, 8 waves 2Mx4N, wave tile 128x64.
// Per K-tile: 4 quadrant phases x 16 MFMA. vmcnt(4) twice per 2-tile iteration.
// LDS per (buf,kh) region: [256 rows][32 el], 2 rows per 128B line, phys 16B chunk
// p = ((row&1)*4 + kchunk) ^ (line&7)  — conflict-free reads+writes (verified r4).
// EPI 0: Hout[m][n] = bf16(w4[m][tn>>4]*gelu(C));  EPI 1: (split?Part:Out)[m][n] = C.
template<int EPI>
__global__ __launch_bounds__(512, 2) void gemm256_kernel(
    const u16* __restrict__ A, const u16* __restrict__ BT,
    const int lda, const int ldb, const int ntn, const int NITER,
    u16* __restrict__ Hout, const int ldh, const float* __restrict__ w4,
    float* __restrict__ Out, float* __restrict__ Part) {
    __shared__ __align__(16) u16 As[32768];
    __shared__ __align__(16) u16 Bs[32768];
    const int tid = threadIdx.x;
    const int w = tid >> 6, lane = tid & 63;
    const int wr = w >> 2, wc = w & 3;

    // bijective XCD chunked swizzle (gridDim.x % 8 == 0)
    const int chunk = gridDim.x >> 3;
    const int swz = ((int)blockIdx.x & 7) * chunk + ((int)blockIdx.x >> 3);
    int tm, tn, split = 0;
    if (EPI == 1) { split = swz & 1; const int t = swz >> 1; tm = t / ntn; tn = t % ntn; }
    else          { tm = swz / ntn; tn = swz % ntn; }
    const u16* Ab = A  + (size_t)split * 8192;
    const u16* Bb = BT + (size_t)split * 8192;

    // staging addressing (linear LDS dest, inverse-swizzled global source)
    const int il = lane >> 3;
    const int cch = (lane & 7) ^ il;
    const int rowoff = il * 2 + (cch >> 2);
    const int kch = cch & 3;
    const u16* gA0 = Ab + (size_t)(tm * 256 + w * 16 + rowoff) * lda + kch * 8;
    const u16* gB0 = Bb + (size_t)(tn * 256 + w * 16 + rowoff) * ldb + kch * 8;

    // fragment read lane offset
    const int rr = lane & 15, kq = lane >> 4;
    const int lfrag = (rr >> 1) * 64 + (((((rr & 1) << 2) | kq) ^ ((rr >> 1) & 7)) << 3);

    f32x4 acc[8][4];
#pragma unroll
    for (int mi = 0; mi < 8; mi++)
#pragma unroll
        for (int nf = 0; nf < 4; nf++) acc[mi][nf] = (f32x4){0.f, 0.f, 0.f, 0.f};
    bf16x8 a[4][2], b[4][2];

    auto stage_a = [&](int tile, int half) {
        const int dst = (tile & 1) * 16384 + half * 4096 + w * 512;
        const u16* src = gA0 + (size_t)half * 128 * lda + (size_t)tile * 64;
        __builtin_amdgcn_global_load_lds((gv_t*)(u16*)src,        (lv_t*)&As[dst],        16, 0, 0);
        __builtin_amdgcn_global_load_lds((gv_t*)(u16*)(src + 32), (lv_t*)&As[dst + 8192], 16, 0, 0);
    };
    auto stage_b = [&](int tile, int half) {
        const int dst = (tile & 1) * 16384 + half * 4096 + w * 512;
        const u16* src = gB0 + (size_t)half * 128 * ldb + (size_t)tile * 64;
        __builtin_amdgcn_global_load_lds((gv_t*)(u16*)src,        (lv_t*)&Bs[dst],        16, 0, 0);
        __builtin_amdgcn_global_load_lds((gv_t*)(u16*)(src + 32), (lv_t*)&Bs[dst + 8192], 16, 0, 0);
    };

#define LOADA(BUF, AQ)                                                         \
    _Pragma("unroll") for (int mi = 0; mi < 4; mi++)                           \
    _Pragma("unroll") for (int kh = 0; kh < 2; kh++)                           \
        a[mi][kh] = *(const bf16x8*)&As[(BUF)*16384 + kh*8192 + wr*4096 + (AQ)*2048 + mi*512 + lfrag];
#define LOADB(BUF, BP)                                                         \
    _Pragma("unroll") for (int nf = 0; nf < 2; nf++)                           \
    _Pragma("unroll") for (int kh = 0; kh < 2; kh++)                           \
        b[(BP)*2+nf][kh] = *(const bf16x8*)&Bs[(BUF)*16384 + kh*8192 + wc*2048 + (BP)*1024 + nf*512 + lfrag];
#define BARA                                                                   \
    __builtin_amdgcn_s_barrier();                                              \
    asm volatile("s_waitcnt lgkmcnt(0)" ::: "memory");                         \
    __builtin_amdgcn_sched_barrier(0);
#define MFQ(MQ, NP)                                                            \
    __builtin_amdgcn_s_setprio(1);                                             \
    _Pragma("unroll") for (int mi = 0; mi < 4; mi++)                           \
    _Pragma("unroll") for (int nf = 0; nf < 2; nf++)                           \
    _Pragma("unroll") for (int kh = 0; kh < 2; kh++)                           \
        acc[(MQ)*4+mi][(NP)*2+nf] = __builtin_amdgcn_mfma_f32_16x16x32_bf16(   \
            a[mi][kh], b[(NP)*2+nf][kh], acc[(MQ)*4+mi][(NP)*2+nf], 0, 0, 0);  \
    __builtin_amdgcn_s_setprio(0);
#define BARB                                                                   \
    __builtin_amdgcn_s_barrier();                                              \
    __builtin_amdgcn_sched_barrier(0);
#define VMW4 asm volatile("s_waitcnt vmcnt(4)" ::: "memory"); __builtin_amdgcn_sched_barrier(0);
#define VMW0 asm volatile("s_waitcnt vmcnt(0)" ::: "memory"); __builtin_amdgcn_sched_barrier(0);

    // prologue: tile0 (A,B) + tile1 (B); wait tile0; barrier
    stage_a(0, 0); stage_a(0, 1); stage_b(0, 0); stage_b(0, 1); stage_b(1, 0); stage_b(1, 1);
    VMW4
    __builtin_amdgcn_s_barrier();
    __builtin_amdgcn_sched_barrier(0);

    for (int s2 = 0; s2 < NITER; ++s2) {
        const int t0 = 2 * s2;
        const bool pf = (s2 + 1 < NITER);
        // ---- tile t0 (buf 0) ----
        LOADA(0, 0) LOADB(0, 0) stage_a(t0 + 1, 0); BARA MFQ(0, 0) BARB
        LOADB(0, 1)             stage_a(t0 + 1, 1); BARA MFQ(0, 1) BARB
        LOADA(0, 1)  if (pf) stage_b(t0 + 2, 0);    BARA MFQ(1, 0) BARB
                     if (pf) stage_b(t0 + 2, 1);    BARA MFQ(1, 1)
        if (pf) { VMW4 } else { VMW0 }              BARB
        // ---- tile t0+1 (buf 1) ----
        LOADA(1, 0) LOADB(1, 0) if (pf) stage_a(t0 + 2, 0); BARA MFQ(0, 0) BARB
        LOADB(1, 1)             if (pf) stage_a(t0 + 2, 1); BARA MFQ(0, 1) BARB
        LOADA(1, 1)             if (pf) stage_b(t0 + 3, 0); BARA MFQ(1, 0) BARB
                                if (pf) stage_b(t0 + 3, 1); BARA MFQ(1, 1)
        if (pf) { VMW4 }                                    BARB
    }
#undef LOADA
#undef LOADB
#undef BARA
#undef MFQ
#undef BARB
#undef VMW4
#undef VMW0

    // ---- epilogue: C/D col = rr, row = kq*4 + q ----
    const int rbase = tm * 256 + wr * 128 + kq * 4;
    const int cbase = tn * 256 + wc * 64 + rr;
    if (EPI == 0) {
        const int e = tn >> 4;  // 16 col-tiles of 256 per 4096-wide expert block
#pragma unroll
        for (int mi = 0; mi < 8; mi++) {
#pragma unroll
            for (int q = 0; q < 4; q++) {
                const int row = rbase + mi * 16 + q;
                const float wgt = w4[(size_t)row * 4 + e];
                u16* hp = Hout + (size_t)row * ldh + cbase;
#pragma unroll
                for (int nf = 0; nf < 4; nf++)
                    hp[nf * 16] = f2bf(wgt * gelu_tanh(acc[mi][nf][q]));
            }
        }
    } else {
        float* dst = split ? Part : Out;
#pragma unroll
        for (int mi = 0; mi < 8; mi++) {
#pragma unroll
            for (int q = 0; q < 4; q++) {
                const int row = rbase + mi * 16 + q;
                float* op = dst + (size_t)row * 1024 + cbase;
#pragma unroll
                for (int nf = 0; nf < 4; nf++) op[nf * 16] = acc[mi][nf][q];
            }
        }
    }
}

// ---------- launch ----------
extern "C" void kernel_launch(void* const* d_in, const int* in_sizes, int n_in,
                              void* d_out, int out_size, void* d_ws, size_t ws_size,
                              hipStream_t stream) {
    (void)in_sizes; (void)n_in; (void)out_size;
    const float* x  = (const float*)d_in[0];
    const float* Wg = (const float*)d_in[1];
    const float* W1 = (const float*)d_in[2];
    const float* A1 = (const float*)d_in[3];
    const float* B1 = (const float*)d_in[4];
    const float* W2 = (const float*)d_in[5];
    const float* A2 = (const float*)d_in[6];
    const float* B2 = (const float*)d_in[7];
    float* out = (float*)d_out;

    const int N = 8192;

    const size_t need = 131072
                      + (size_t)8192 * 1024 * 2
                      + (size_t)8192 * 16384 * 2
                      + (size_t)16384 * 1024 * 2
                      + (size_t)1024 * 16384 * 2;
    if (ws_size < need) return;  // fail visibly rather than corrupt

    char* p = (char*)d_ws;
    float* w4 = (float*)p; p += 131072;
    u16* Xe   = (u16*)p;   p += (size_t)8192 * 1024 * 2;
    u16* Hs   = (u16*)p;   p += (size_t)8192 * 16384 * 2;
    u16* W1T  = (u16*)p;   p += (size_t)16384 * 1024 * 2;   // reused as fp32 split-K partial
    u16* W2T  = (u16*)p;   p += (size_t)1024 * 16384 * 2;
    float* part = (float*)W1T;  // 8192*1024*4 B == 16384*1024*2 B

    gate_kernel<<<N / 4, 256, 0, stream>>>(x, Wg, w4);
    cast_x_kernel<<<2048, 256, 0, stream>>>(x, Xe, N * 1024 / 8);
    // W1eff^T[e*4096+f][k] = bf16(W1[e][k][f] + sum_r A1[e][k][r]*B1[e][r][f])
    weff_kernel<<<dim3(128, 32, 4), dim3(32, 8), 0, stream>>>(
        W1, A1, B1, W1T, 4096, 1024,
        (size_t)1024 * 4096, (size_t)1024 * 16, (size_t)16 * 4096, (size_t)4096 * 1024);
    // W2eff^T[d][e*4096+k] = bf16(W2[e][k][d] + sum_r A2[e][k][r]*B2[e][r][d])
    weff_kernel<<<dim3(32, 128, 4), dim3(32, 8), 0, stream>>>(
        W2, A2, B2, W2T, 1024, 16384,
        (size_t)4096 * 1024, (size_t)4096 * 16, (size_t)16 * 1024, (size_t)4096);
    // GEMM1: Hs[m][e*4096+f] = bf16(w4[m][e] * gelu(Xe @ W1eff^T)); grid 32x64
    gemm256_kernel<0><<<2048, 512, 0, stream>>>(
        Xe, W1T, 1024, 1024, 64, 8, Hs, 16384, w4, nullptr, nullptr);
    // GEMM2: split-K x2 over K=16384; split0 -> out, split1 -> part; grid 2x32x4
    gemm256_kernel<1><<<256, 512, 0, stream>>>(
        Hs, W2T, 16384, 16384, 4, 64, nullptr, 0, nullptr, out, part);
    add_kernel<<<2048, 256, 0, stream>>>(out, part, N * 1024 / 4);
}